// Round 12
// baseline (400.718 us; speedup 1.0000x reference)
//
#include <hip/hip_runtime.h>

#define NN 100000
#define NE 1600000
#define NB 391      // ceil(NN/256)
#define RS 32768    // nodes per k-range
#define KR 4        // ranges (4*32768 >= NN)
#define RSL 64      // edge slices
#define SLICE 25000 // NE / RSL

typedef unsigned int uint;
typedef unsigned short ushort;
typedef unsigned char uchar;
typedef __attribute__((ext_vector_type(8))) short short8;   // 8 bf16 MFMA frag
typedef __attribute__((ext_vector_type(4))) float f32x4;    // MFMA acc / nt-vector

__device__ __forceinline__ ushort f2bf(float f) {      // RNE fp32 -> bf16
    uint u = __float_as_uint(f);
    return (ushort)((u + 0x7FFFu + ((u >> 16) & 1u)) >> 16);
}

// decode 8 bf16 from a uint4 and add into acc[8]
__device__ __forceinline__ void bf8_add(uint4 q, float* acc) {
    acc[0] += __uint_as_float(q.x << 16);
    acc[1] += __uint_as_float(q.x & 0xFFFF0000u);
    acc[2] += __uint_as_float(q.y << 16);
    acc[3] += __uint_as_float(q.y & 0xFFFF0000u);
    acc[4] += __uint_as_float(q.z << 16);
    acc[5] += __uint_as_float(q.z & 0xFFFF0000u);
    acc[6] += __uint_as_float(q.w << 16);
    acc[7] += __uint_as_float(q.w & 0xFFFF0000u);
}

// ---------------- LDS-privatized degree histograms (no global atomics) ----------

__global__ __launch_bounds__(256)
void k_hist(const int* __restrict__ src, const int* __restrict__ dst,
            uchar* __restrict__ pout, uchar* __restrict__ pin) {
    int k = blockIdx.x >> 6, r = blockIdx.x & 63;
    __shared__ uint ho[RS / 4], hi[RS / 4];
    for (int i = threadIdx.x; i < RS / 4; i += 256) { ho[i] = 0; hi[i] = 0; }
    __syncthreads();
    int base = k * RS;
    int lo = r * SLICE, hiend = lo + SLICE;
    for (int i = lo + threadIdx.x; i < hiend; i += 256) {
        int s = src[i] - base;
        if ((uint)s < RS) atomicAdd(&ho[s >> 2], 1u << (8 * (s & 3)));
        int d = dst[i] - base;
        if ((uint)d < RS) atomicAdd(&hi[d >> 2], 1u << (8 * (d & 3)));
    }
    __syncthreads();
    uint* po = (uint*)(pout + ((size_t)k * RSL + r) * RS);
    uint* pi = (uint*)(pin + ((size_t)k * RSL + r) * RS);
    for (int i = threadIdx.x; i < RS / 4; i += 256) { po[i] = ho[i]; pi[i] = hi[i]; }
}

// ------- reduce partials -> norms/degrees; pin -> r-prefix; fused blocksum ------

__global__ __launch_bounds__(256)
void k_red(const uchar* __restrict__ pout, uchar* __restrict__ pin,
           float* __restrict__ ns, float* __restrict__ nd,
           int* __restrict__ csum, int* __restrict__ bsum) {
    __shared__ int sred[256];
    int t = threadIdx.x;
    int n = blockIdx.x * 256 + t;
    int si = 0;
    if (n < NN) {
        int k = n >> 15, j = n & (RS - 1);
        const uchar* po = pout + (size_t)k * RSL * RS + j;
        uchar* pi = pin + (size_t)k * RSL * RS + j;
        int so = 0;
        #pragma unroll
        for (int r = 0; r < RSL; ++r) so += po[(size_t)r * RS];
        #pragma unroll
        for (int r = 0; r < RSL; ++r) {
            uchar c = pi[(size_t)r * RS];
            pi[(size_t)r * RS] = (uchar)si;     // exclusive prefix along r
            si += c;
        }
        ns[n] = (so > 0) ? rsqrtf((float)so) : 0.f;
        nd[n] = (si > 0) ? rsqrtf((float)si) : 0.f;
        csum[n] = si;
    }
    sred[t] = si;
    __syncthreads();
    for (int off = 128; off > 0; off >>= 1) {
        if (t < off) sred[t] += sred[t + off];
        __syncthreads();
    }
    if (t == 0) bsum[blockIdx.x] = sred[0];
}

// ---------------- scan: block sums -> exclusive block offsets ----------------

__global__ void k_scanb(const int* __restrict__ bsum, int* __restrict__ bsumex,
                        int* __restrict__ rowptr) {
    __shared__ int s[512];
    int t = threadIdx.x;
    int v = (t < NB) ? bsum[t] : 0;
    s[t] = v;
    __syncthreads();
    for (int off = 1; off < 512; off <<= 1) {
        int add = (t >= off) ? s[t - off] : 0;
        __syncthreads();
        s[t] += add;
        __syncthreads();
    }
    if (t < NB) bsumex[t] = s[t] - v;
    if (t == 0) rowptr[NN] = NE;
}

__global__ void k_rowptr(const int* __restrict__ cnt, const int* __restrict__ bsumex,
                         int* __restrict__ rowptr) {
    __shared__ int s[256];
    int t = threadIdx.x;
    int i = blockIdx.x * 256 + t;
    int v = (i < NN) ? cnt[i] : 0;
    s[t] = v;
    __syncthreads();
    for (int off = 1; off < 256; off <<= 1) {
        int add = (t >= off) ? s[t - off] : 0;
        __syncthreads();
        s[t] += add;
        __syncthreads();
    }
    if (i < NN) rowptr[i] = bsumex[blockIdx.x] + s[t] - v;
}

// ---------------- CSR fill via LDS cursors (no global atomics) ----------------

__global__ __launch_bounds__(256)
void k_fill(const int* __restrict__ src, const int* __restrict__ dst,
            const uchar* __restrict__ pin, const int* __restrict__ rowptr,
            int* __restrict__ csrc) {
    int k = blockIdx.x >> 6, r = blockIdx.x & 63;
    __shared__ uint cur[RS / 2];
    const uchar* pi = pin + ((size_t)k * RSL + r) * RS;
    for (int i = threadIdx.x; i < RS / 2; i += 256) {
        uint a = pi[2 * i], b = pi[2 * i + 1];
        cur[i] = a | (b << 16);
    }
    __syncthreads();
    int base = k * RS;
    int lo = r * SLICE, hiend = lo + SLICE;
    for (int i = lo + threadIdx.x; i < hiend; i += 256) {
        int d = dst[i];
        int j = d - base;
        if ((uint)j < RS) {
            uint old = atomicAdd(&cur[j >> 1], 1u << (16 * (j & 1)));
            int p = (old >> (16 * (j & 1))) & 0xFFFF;
            csrc[rowptr[d] + p] = src[i];
        }
    }
}

// ------------- all W transposes -> bf16, one kernel (WT[n][k]=bf16(W[k][n])) -----

__global__ void k_wtall(const float* __restrict__ W0, const float* __restrict__ W1,
                        const float* __restrict__ W2, ushort* __restrict__ WT) {
    int i = blockIdx.x * 256 + threadIdx.x;      // 40960 total
    if (i < 16384) {
        int n = i >> 7, k = i & 127;
        WT[i] = f2bf(W0[k * 128 + n]);
    } else if (i < 32768) {
        int j = i - 16384; int n = j >> 7, k = j & 127;
        WT[i] = f2bf(W1[k * 128 + n]);
    } else if (i < 40960) {
        int j = i - 32768; int n = j >> 7, k = j & 127;
        WT[i] = f2bf(W2[k * 64 + n]);
    }
}

// -------- layer-1 GEMM: Y0b = bf16(ns*(x@W0)); wave0 also copies x -> out0 -------
// x loads / out0 stores are NONTEMPORAL (read-once / write-only streams) via
// the native-vector f32x4 type (clang rejects HIP float4 for nt builtins).

__global__ __launch_bounds__(256)
void k_gemm1(const float* __restrict__ A, const ushort* __restrict__ WT,
             const float* __restrict__ ns, ushort* __restrict__ Cb,
             float* __restrict__ xout) {
    int tid = threadIdx.x;
    int w = tid >> 6;
    int l = tid & 63;
    int li = l & 15;
    int kg = l >> 4;           // 0..3
    short8 bfrag[2][4];
    #pragma unroll
    for (int n = 0; n < 2; ++n) {
        int col = w * 32 + n * 16 + li;
        #pragma unroll
        for (int kt = 0; kt < 4; ++kt)
            bfrag[n][kt] = *(const short8*)(WT + (size_t)col * 128 + kt * 32 + kg * 8);
    }
    for (int mg = blockIdx.x; mg < NN / 16; mg += gridDim.x) {
        int row = mg * 16 + li;
        short8 afrag[4];
        #pragma unroll
        for (int kt = 0; kt < 4; ++kt) {
            const float* ap = A + (size_t)row * 128 + kt * 32 + kg * 8;
            f32x4 a0 = __builtin_nontemporal_load((const f32x4*)ap);
            f32x4 a1 = __builtin_nontemporal_load((const f32x4*)(ap + 4));
            if (w == 0) {   // fused x-passthrough (each tile covered once)
                float* op = xout + (size_t)row * 128 + kt * 32 + kg * 8;
                __builtin_nontemporal_store(a0, (f32x4*)op);
                __builtin_nontemporal_store(a1, (f32x4*)(op + 4));
            }
            short8 af;
            af[0] = (short)f2bf(a0.x); af[1] = (short)f2bf(a0.y);
            af[2] = (short)f2bf(a0.z); af[3] = (short)f2bf(a0.w);
            af[4] = (short)f2bf(a1.x); af[5] = (short)f2bf(a1.y);
            af[6] = (short)f2bf(a1.z); af[7] = (short)f2bf(a1.w);
            afrag[kt] = af;
        }
        int crow = mg * 16 + kg * 4;
        float4 nsv = *(const float4*)(ns + crow);     // crow % 4 == 0
        float nsa[4] = {nsv.x, nsv.y, nsv.z, nsv.w};
        #pragma unroll
        for (int n = 0; n < 2; ++n) {
            f32x4 acc = {0.f, 0.f, 0.f, 0.f};
            #pragma unroll
            for (int kt = 0; kt < 4; ++kt)
                acc = __builtin_amdgcn_mfma_f32_16x16x32_bf16(afrag[kt], bfrag[n][kt], acc, 0, 0, 0);
            int ccol = w * 32 + n * 16 + li;
            #pragma unroll
            for (int r = 0; r < 4; ++r)
                Cb[(size_t)(crow + r) * 128 + ccol] = f2bf(acc[r] * nsa[r]);
        }
    }
}

// ------- fused agg + next-layer GEMM -------------------------------------------
// Phase 1: h = relu(nd * sum_e Yb[src_e] + b)  (16 nodes/block; h stored
//          NONTEMPORAL - final output, never re-read on GPU).
// Phase 2: Yout = bf16(ns * (h @ W)) via MFMA (A from LDS, B from L2-hot WT);
//          Yout cached (it is gathered by the next kernel).

template<int NOUT>
__global__ __launch_bounds__(256)
void k_agg_gemm(const ushort* __restrict__ Yb, const int* __restrict__ rowptr,
                const int* __restrict__ csrc, const float* __restrict__ nd,
                const float* __restrict__ bias, const float* __restrict__ ns,
                const ushort* __restrict__ WT, float* __restrict__ hout,
                ushort* __restrict__ Yout) {
    constexpr int NT = NOUT / 64;
    __shared__ ushort sA[16][136];      // +8 bf16 pad breaks bank alignment
    int tid = threadIdx.x;
    int grp = tid >> 4;
    int lane = tid & 15;
    int node_base = blockIdx.x * 16;
    int node = node_base + grp;
    int beg = rowptr[node], end = rowptr[node + 1];
    float acc[8] = {0.f, 0.f, 0.f, 0.f, 0.f, 0.f, 0.f, 0.f};
    int e = beg;
    for (; e + 7 < end; e += 8) {              // 8 gathers in flight
        int s0 = csrc[e];     int s1 = csrc[e + 1];
        int s2 = csrc[e + 2]; int s3 = csrc[e + 3];
        int s4 = csrc[e + 4]; int s5 = csrc[e + 5];
        int s6 = csrc[e + 6]; int s7 = csrc[e + 7];
        uint4 q0 = *(const uint4*)(Yb + (size_t)s0 * 128 + lane * 8);
        uint4 q1 = *(const uint4*)(Yb + (size_t)s1 * 128 + lane * 8);
        uint4 q2 = *(const uint4*)(Yb + (size_t)s2 * 128 + lane * 8);
        uint4 q3 = *(const uint4*)(Yb + (size_t)s3 * 128 + lane * 8);
        uint4 q4 = *(const uint4*)(Yb + (size_t)s4 * 128 + lane * 8);
        uint4 q5 = *(const uint4*)(Yb + (size_t)s5 * 128 + lane * 8);
        uint4 q6 = *(const uint4*)(Yb + (size_t)s6 * 128 + lane * 8);
        uint4 q7 = *(const uint4*)(Yb + (size_t)s7 * 128 + lane * 8);
        bf8_add(q0, acc); bf8_add(q1, acc); bf8_add(q2, acc); bf8_add(q3, acc);
        bf8_add(q4, acc); bf8_add(q5, acc); bf8_add(q6, acc); bf8_add(q7, acc);
    }
    for (; e + 3 < end; e += 4) {
        int s0 = csrc[e];     int s1 = csrc[e + 1];
        int s2 = csrc[e + 2]; int s3 = csrc[e + 3];
        uint4 q0 = *(const uint4*)(Yb + (size_t)s0 * 128 + lane * 8);
        uint4 q1 = *(const uint4*)(Yb + (size_t)s1 * 128 + lane * 8);
        uint4 q2 = *(const uint4*)(Yb + (size_t)s2 * 128 + lane * 8);
        uint4 q3 = *(const uint4*)(Yb + (size_t)s3 * 128 + lane * 8);
        bf8_add(q0, acc); bf8_add(q1, acc); bf8_add(q2, acc); bf8_add(q3, acc);
    }
    for (; e < end; ++e) {
        uint4 q = *(const uint4*)(Yb + (size_t)csrc[e] * 128 + lane * 8);
        bf8_add(q, acc);
    }
    float ndv = nd[node];
    float4 b0 = *(const float4*)(bias + lane * 8);
    float4 b1 = *(const float4*)(bias + lane * 8 + 4);
    float o[8];
    o[0] = fmaxf(acc[0] * ndv + b0.x, 0.f); o[1] = fmaxf(acc[1] * ndv + b0.y, 0.f);
    o[2] = fmaxf(acc[2] * ndv + b0.z, 0.f); o[3] = fmaxf(acc[3] * ndv + b0.w, 0.f);
    o[4] = fmaxf(acc[4] * ndv + b1.x, 0.f); o[5] = fmaxf(acc[5] * ndv + b1.y, 0.f);
    o[6] = fmaxf(acc[6] * ndv + b1.z, 0.f); o[7] = fmaxf(acc[7] * ndv + b1.w, 0.f);
    f32x4 ov0 = {o[0], o[1], o[2], o[3]};
    f32x4 ov1 = {o[4], o[5], o[6], o[7]};
    __builtin_nontemporal_store(ov0, (f32x4*)(hout + (size_t)node * 128 + lane * 8));
    __builtin_nontemporal_store(ov1, (f32x4*)(hout + (size_t)node * 128 + lane * 8 + 4));
    short8 ob;
    #pragma unroll
    for (int i = 0; i < 8; ++i) ob[i] = (short)f2bf(o[i]);
    *(short8*)&sA[grp][lane * 8] = ob;    // grp*272B + lane*16B: 16-B aligned
    __syncthreads();

    // phase 2: MFMA over the 16x128 LDS tile
    int w = tid >> 6;
    int l = tid & 63;
    int li = l & 15;
    int kg = l >> 4;
    short8 afrag[4];
    #pragma unroll
    for (int kt = 0; kt < 4; ++kt)
        afrag[kt] = *(const short8*)&sA[li][kt * 32 + kg * 8];
    float4 nsv = *(const float4*)(ns + node_base + kg * 4);
    float nsa[4] = {nsv.x, nsv.y, nsv.z, nsv.w};
    #pragma unroll
    for (int n = 0; n < NT; ++n) {
        int col = w * 16 * NT + n * 16 + li;
        short8 bfrag[4];
        #pragma unroll
        for (int kt = 0; kt < 4; ++kt)
            bfrag[kt] = *(const short8*)(WT + (size_t)col * 128 + kt * 32 + kg * 8);
        f32x4 acc2 = {0.f, 0.f, 0.f, 0.f};
        #pragma unroll
        for (int kt = 0; kt < 4; ++kt)
            acc2 = __builtin_amdgcn_mfma_f32_16x16x32_bf16(afrag[kt], bfrag[kt], acc2, 0, 0, 0);
        #pragma unroll
        for (int r = 0; r < 4; ++r)
            Yout[(size_t)(node_base + kg * 4 + r) * NOUT + col] = f2bf(acc2[r] * nsa[r]);
    }
}

// 256 thr = 32 groups x 8 lanes; one node per group; lane owns 8 of 64 feats.
// h3 stores are NONTEMPORAL (final output).
__global__ __launch_bounds__(256)
void k_agg64(const ushort* __restrict__ Yb, const int* __restrict__ rowptr,
             const int* __restrict__ csrc, const float* __restrict__ nd,
             const float* __restrict__ bias, float* __restrict__ out) {
    int tid = threadIdx.x;
    int grp = tid >> 3;
    int lane = tid & 7;
    int node = blockIdx.x * 32 + grp;
    int beg = rowptr[node], end = rowptr[node + 1];
    float acc[8] = {0.f, 0.f, 0.f, 0.f, 0.f, 0.f, 0.f, 0.f};
    int e = beg;
    for (; e + 7 < end; e += 8) {
        int s0 = csrc[e];     int s1 = csrc[e + 1];
        int s2 = csrc[e + 2]; int s3 = csrc[e + 3];
        int s4 = csrc[e + 4]; int s5 = csrc[e + 5];
        int s6 = csrc[e + 6]; int s7 = csrc[e + 7];
        uint4 q0 = *(const uint4*)(Yb + (size_t)s0 * 64 + lane * 8);
        uint4 q1 = *(const uint4*)(Yb + (size_t)s1 * 64 + lane * 8);
        uint4 q2 = *(const uint4*)(Yb + (size_t)s2 * 64 + lane * 8);
        uint4 q3 = *(const uint4*)(Yb + (size_t)s3 * 64 + lane * 8);
        uint4 q4 = *(const uint4*)(Yb + (size_t)s4 * 64 + lane * 8);
        uint4 q5 = *(const uint4*)(Yb + (size_t)s5 * 64 + lane * 8);
        uint4 q6 = *(const uint4*)(Yb + (size_t)s6 * 64 + lane * 8);
        uint4 q7 = *(const uint4*)(Yb + (size_t)s7 * 64 + lane * 8);
        bf8_add(q0, acc); bf8_add(q1, acc); bf8_add(q2, acc); bf8_add(q3, acc);
        bf8_add(q4, acc); bf8_add(q5, acc); bf8_add(q6, acc); bf8_add(q7, acc);
    }
    for (; e + 3 < end; e += 4) {
        int s0 = csrc[e];     int s1 = csrc[e + 1];
        int s2 = csrc[e + 2]; int s3 = csrc[e + 3];
        uint4 q0 = *(const uint4*)(Yb + (size_t)s0 * 64 + lane * 8);
        uint4 q1 = *(const uint4*)(Yb + (size_t)s1 * 64 + lane * 8);
        uint4 q2 = *(const uint4*)(Yb + (size_t)s2 * 64 + lane * 8);
        uint4 q3 = *(const uint4*)(Yb + (size_t)s3 * 64 + lane * 8);
        bf8_add(q0, acc); bf8_add(q1, acc); bf8_add(q2, acc); bf8_add(q3, acc);
    }
    for (; e < end; ++e) {
        uint4 q = *(const uint4*)(Yb + (size_t)csrc[e] * 64 + lane * 8);
        bf8_add(q, acc);
    }
    float ndv = nd[node];
    float4 b0 = *(const float4*)(bias + lane * 8);
    float4 b1 = *(const float4*)(bias + lane * 8 + 4);
    f32x4 o0, o1;
    o0.x = acc[0] * ndv + b0.x; o0.y = acc[1] * ndv + b0.y;
    o0.z = acc[2] * ndv + b0.z; o0.w = acc[3] * ndv + b0.w;
    o1.x = acc[4] * ndv + b1.x; o1.y = acc[5] * ndv + b1.y;
    o1.z = acc[6] * ndv + b1.z; o1.w = acc[7] * ndv + b1.w;
    __builtin_nontemporal_store(o0, (f32x4*)(out + (size_t)node * 64 + lane * 8));
    __builtin_nontemporal_store(o1, (f32x4*)(out + (size_t)node * 64 + lane * 8 + 4));
}

// ---------------- launch ----------------

extern "C" void kernel_launch(void* const* d_in, const int* in_sizes, int n_in,
                              void* d_out, int out_size, void* d_ws, size_t ws_size,
                              hipStream_t stream) {
    const float* x  = (const float*)d_in[0];
    const int* esrc = (const int*)d_in[1];
    const int* edst = (const int*)d_in[2];
    const float* W0 = (const float*)d_in[3];
    const float* b0 = (const float*)d_in[4];
    const float* W1 = (const float*)d_in[5];
    const float* b1 = (const float*)d_in[6];
    const float* W2 = (const float*)d_in[7];
    const float* b2 = (const float*)d_in[8];
    float* out = (float*)d_out;

    // workspace (~40 MB). No trailing backslashes in comments.
    float* ns      = (float*)d_ws;                // NN
    float* nd      = ns + NN;                     // NN
    int*   csum    = (int*)(nd + NN);             // NN
    int*   rowptr  = csum + NN;                   // NN+8
    int*   bsum    = rowptr + NN + 8;             // 512
    int*   bsumex  = bsum + 512;                  // 512
    int*   csrc    = bsumex + 512;                // NE
    uchar* pout    = (uchar*)(csrc + NE);         // KR*RSL*RS = 8 MB
    uchar* pin     = pout + (size_t)KR * RSL * RS;// 8 MB
    ushort* WT0    = (ushort*)(pin + (size_t)KR * RSL * RS);  // 128*128
    ushort* WT1    = WT0 + 128 * 128;             // 128*128
    ushort* WT2    = WT1 + 128 * 128;             // 64*128
    ushort* Y2b    = WT2 + 64 * 128;              // NN*64 bf16

    // output chunks
    float* h1 = out + (size_t)NN * 128;
    float* h2 = h1 + (size_t)NN * 128;
    float* h3 = h2 + (size_t)NN * 128;            // NN*64 floats

    // bf16 GEMM outputs parked in dead output slots:
    //  Y0b in h2 slot (last read: aggGemm layer1; h2 written layer2)
    //  Y1b in h3 slot (last read: aggGemm layer2; h3 written agg64)
    ushort* Y0b = (ushort*)h2;                    // NN*128 bf16
    ushort* Y1b = (ushort*)h3;                    // NN*128 bf16

    // 1. degree histograms (LDS-privatized, no global atomics)
    k_hist<<<KR * RSL, 256, 0, stream>>>(esrc, edst, pout, pin);

    // 2. reduce -> ns/nd/csum (+fused block sums); pin becomes r-prefix
    k_red<<<NB, 256, 0, stream>>>(pout, pin, ns, nd, csum, bsum);

    // 3. scan -> rowptr
    k_scanb<<<1, 512, 0, stream>>>(bsum, bsumex, rowptr);
    k_rowptr<<<NB, 256, 0, stream>>>(csum, bsumex, rowptr);

    // 4. fill CSR via LDS cursors (no global atomics)
    k_fill<<<KR * RSL, 256, 0, stream>>>(esrc, edst, pin, rowptr, csrc);

    // 5. weight transposes (one kernel)
    k_wtall<<<160, 256, 0, stream>>>(W0, W1, W2, WT0);

    // 6. layer-1 GEMM (nt-reads fp32 x, nt-writes out0 passthrough)
    k_gemm1<<<1024, 256, 0, stream>>>(x, WT0, ns, Y0b, out);

    // 7. fused agg(layer1)+GEMM(layer2): h1 (nt) + Y1b (cached)
    k_agg_gemm<128><<<NN / 16, 256, 0, stream>>>(Y0b, rowptr, csrc, nd, b0, ns,
                                                 WT1, h1, Y1b);

    // 8. fused agg(layer2)+GEMM(layer3): h2 (nt) + Y2b (cached)
    k_agg_gemm<64><<<NN / 16, 256, 0, stream>>>(Y1b, rowptr, csrc, nd, b1, ns,
                                                WT2, h2, Y2b);

    // 9. final aggregation -> h3 (nt)
    k_agg64<<<NN / 32, 256, 0, stream>>>(Y2b, rowptr, csrc, nd, b2, h3);
}

// Round 13
// 387.083 us; speedup vs baseline: 1.0352x; 1.0352x over previous
//
#include <hip/hip_runtime.h>

#define NN 100000
#define NE 1600000
#define NB 391      // ceil(NN/256)
#define RS 32768    // nodes per k-range
#define KR 4        // ranges (4*32768 >= NN)
#define RSL 64      // edge slices
#define SLICE 25000 // NE / RSL

typedef unsigned int uint;
typedef unsigned short ushort;
typedef unsigned char uchar;
typedef __attribute__((ext_vector_type(8))) short short8;   // 8 bf16 MFMA frag
typedef __attribute__((ext_vector_type(4))) float f32x4;    // MFMA acc

__device__ __forceinline__ ushort f2bf(float f) {      // RNE fp32 -> bf16
    uint u = __float_as_uint(f);
    return (ushort)((u + 0x7FFFu + ((u >> 16) & 1u)) >> 16);
}

// decode 8 bf16 from a uint4 and add into acc[8]
__device__ __forceinline__ void bf8_add(uint4 q, float* acc) {
    acc[0] += __uint_as_float(q.x << 16);
    acc[1] += __uint_as_float(q.x & 0xFFFF0000u);
    acc[2] += __uint_as_float(q.y << 16);
    acc[3] += __uint_as_float(q.y & 0xFFFF0000u);
    acc[4] += __uint_as_float(q.z << 16);
    acc[5] += __uint_as_float(q.z & 0xFFFF0000u);
    acc[6] += __uint_as_float(q.w << 16);
    acc[7] += __uint_as_float(q.w & 0xFFFF0000u);
}

// ---------------- LDS-privatized degree histograms (no global atomics) ----------

__global__ __launch_bounds__(256)
void k_hist(const int* __restrict__ src, const int* __restrict__ dst,
            uchar* __restrict__ pout, uchar* __restrict__ pin) {
    int k = blockIdx.x >> 6, r = blockIdx.x & 63;
    __shared__ uint ho[RS / 4], hi[RS / 4];
    for (int i = threadIdx.x; i < RS / 4; i += 256) { ho[i] = 0; hi[i] = 0; }
    __syncthreads();
    int base = k * RS;
    int lo = r * SLICE, hiend = lo + SLICE;
    for (int i = lo + threadIdx.x; i < hiend; i += 256) {
        int s = src[i] - base;
        if ((uint)s < RS) atomicAdd(&ho[s >> 2], 1u << (8 * (s & 3)));
        int d = dst[i] - base;
        if ((uint)d < RS) atomicAdd(&hi[d >> 2], 1u << (8 * (d & 3)));
    }
    __syncthreads();
    uint* po = (uint*)(pout + ((size_t)k * RSL + r) * RS);
    uint* pi = (uint*)(pin + ((size_t)k * RSL + r) * RS);
    for (int i = threadIdx.x; i < RS / 4; i += 256) { po[i] = ho[i]; pi[i] = hi[i]; }
}

// ------- reduce partials -> norms/degrees; pin -> r-prefix; fused blocksum ------

__global__ __launch_bounds__(256)
void k_red(const uchar* __restrict__ pout, uchar* __restrict__ pin,
           float* __restrict__ ns, float* __restrict__ nd,
           int* __restrict__ csum, int* __restrict__ bsum) {
    __shared__ int sred[256];
    int t = threadIdx.x;
    int n = blockIdx.x * 256 + t;
    int si = 0;
    if (n < NN) {
        int k = n >> 15, j = n & (RS - 1);
        const uchar* po = pout + (size_t)k * RSL * RS + j;
        uchar* pi = pin + (size_t)k * RSL * RS + j;
        int so = 0;
        #pragma unroll
        for (int r = 0; r < RSL; ++r) so += po[(size_t)r * RS];
        #pragma unroll
        for (int r = 0; r < RSL; ++r) {
            uchar c = pi[(size_t)r * RS];
            pi[(size_t)r * RS] = (uchar)si;     // exclusive prefix along r
            si += c;
        }
        ns[n] = (so > 0) ? rsqrtf((float)so) : 0.f;
        nd[n] = (si > 0) ? rsqrtf((float)si) : 0.f;
        csum[n] = si;
    }
    sred[t] = si;
    __syncthreads();
    for (int off = 128; off > 0; off >>= 1) {
        if (t < off) sred[t] += sred[t + off];
        __syncthreads();
    }
    if (t == 0) bsum[blockIdx.x] = sred[0];
}

// ---------------- scan: block sums -> exclusive block offsets ----------------

__global__ void k_scanb(const int* __restrict__ bsum, int* __restrict__ bsumex,
                        int* __restrict__ rowptr) {
    __shared__ int s[512];
    int t = threadIdx.x;
    int v = (t < NB) ? bsum[t] : 0;
    s[t] = v;
    __syncthreads();
    for (int off = 1; off < 512; off <<= 1) {
        int add = (t >= off) ? s[t - off] : 0;
        __syncthreads();
        s[t] += add;
        __syncthreads();
    }
    if (t < NB) bsumex[t] = s[t] - v;
    if (t == 0) rowptr[NN] = NE;
}

__global__ void k_rowptr(const int* __restrict__ cnt, const int* __restrict__ bsumex,
                         int* __restrict__ rowptr) {
    __shared__ int s[256];
    int t = threadIdx.x;
    int i = blockIdx.x * 256 + t;
    int v = (i < NN) ? cnt[i] : 0;
    s[t] = v;
    __syncthreads();
    for (int off = 1; off < 256; off <<= 1) {
        int add = (t >= off) ? s[t - off] : 0;
        __syncthreads();
        s[t] += add;
        __syncthreads();
    }
    if (i < NN) rowptr[i] = bsumex[blockIdx.x] + s[t] - v;
}

// ---------------- CSR fill via LDS cursors (no global atomics) ----------------

__global__ __launch_bounds__(256)
void k_fill(const int* __restrict__ src, const int* __restrict__ dst,
            const uchar* __restrict__ pin, const int* __restrict__ rowptr,
            int* __restrict__ csrc) {
    int k = blockIdx.x >> 6, r = blockIdx.x & 63;
    __shared__ uint cur[RS / 2];
    const uchar* pi = pin + ((size_t)k * RSL + r) * RS;
    for (int i = threadIdx.x; i < RS / 2; i += 256) {
        uint a = pi[2 * i], b = pi[2 * i + 1];
        cur[i] = a | (b << 16);
    }
    __syncthreads();
    int base = k * RS;
    int lo = r * SLICE, hiend = lo + SLICE;
    for (int i = lo + threadIdx.x; i < hiend; i += 256) {
        int d = dst[i];
        int j = d - base;
        if ((uint)j < RS) {
            uint old = atomicAdd(&cur[j >> 1], 1u << (16 * (j & 1)));
            int p = (old >> (16 * (j & 1))) & 0xFFFF;
            csrc[rowptr[d] + p] = src[i];
        }
    }
}

// ------------- all W transposes -> bf16, one kernel (WT[n][k]=bf16(W[k][n])) -----

__global__ void k_wtall(const float* __restrict__ W0, const float* __restrict__ W1,
                        const float* __restrict__ W2, ushort* __restrict__ WT) {
    int i = blockIdx.x * 256 + threadIdx.x;      // 40960 total
    if (i < 16384) {
        int n = i >> 7, k = i & 127;
        WT[i] = f2bf(W0[k * 128 + n]);
    } else if (i < 32768) {
        int j = i - 16384; int n = j >> 7, k = j & 127;
        WT[i] = f2bf(W1[k * 128 + n]);
    } else if (i < 40960) {
        int j = i - 32768; int n = j >> 7, k = j & 127;
        WT[i] = f2bf(W2[k * 64 + n]);
    }
}

// -------- layer-1 GEMM: Y0b = bf16(ns*(x@W0)); wave0 also copies x -> out0 -------
// (plain cached loads/stores: round-12 measured nontemporal hints as a -3.5%
//  regression here - do not reintroduce them)

__global__ __launch_bounds__(256)
void k_gemm1(const float* __restrict__ A, const ushort* __restrict__ WT,
             const float* __restrict__ ns, ushort* __restrict__ Cb,
             float* __restrict__ xout) {
    int tid = threadIdx.x;
    int w = tid >> 6;
    int l = tid & 63;
    int li = l & 15;
    int kg = l >> 4;           // 0..3
    short8 bfrag[2][4];
    #pragma unroll
    for (int n = 0; n < 2; ++n) {
        int col = w * 32 + n * 16 + li;
        #pragma unroll
        for (int kt = 0; kt < 4; ++kt)
            bfrag[n][kt] = *(const short8*)(WT + (size_t)col * 128 + kt * 32 + kg * 8);
    }
    for (int mg = blockIdx.x; mg < NN / 16; mg += gridDim.x) {
        int row = mg * 16 + li;
        short8 afrag[4];
        #pragma unroll
        for (int kt = 0; kt < 4; ++kt) {
            const float* ap = A + (size_t)row * 128 + kt * 32 + kg * 8;
            float4 a0 = *(const float4*)ap;
            float4 a1 = *(const float4*)(ap + 4);
            if (w == 0) {   // fused x-passthrough (each tile covered once)
                float* op = xout + (size_t)row * 128 + kt * 32 + kg * 8;
                *(float4*)op = a0;
                *(float4*)(op + 4) = a1;
            }
            short8 af;
            af[0] = (short)f2bf(a0.x); af[1] = (short)f2bf(a0.y);
            af[2] = (short)f2bf(a0.z); af[3] = (short)f2bf(a0.w);
            af[4] = (short)f2bf(a1.x); af[5] = (short)f2bf(a1.y);
            af[6] = (short)f2bf(a1.z); af[7] = (short)f2bf(a1.w);
            afrag[kt] = af;
        }
        int crow = mg * 16 + kg * 4;
        float4 nsv = *(const float4*)(ns + crow);     // crow % 4 == 0
        float nsa[4] = {nsv.x, nsv.y, nsv.z, nsv.w};
        #pragma unroll
        for (int n = 0; n < 2; ++n) {
            f32x4 acc = {0.f, 0.f, 0.f, 0.f};
            #pragma unroll
            for (int kt = 0; kt < 4; ++kt)
                acc = __builtin_amdgcn_mfma_f32_16x16x32_bf16(afrag[kt], bfrag[n][kt], acc, 0, 0, 0);
            int ccol = w * 32 + n * 16 + li;
            #pragma unroll
            for (int r = 0; r < 4; ++r)
                Cb[(size_t)(crow + r) * 128 + ccol] = f2bf(acc[r] * nsa[r]);
        }
    }
}

// ------- fused agg + next-layer GEMM -------------------------------------------
// Phase 1: h = relu(nd * sum_e Yb[src_e] + b)  (16 nodes/block, fp32 out,
//          bf16 copy staged in padded LDS tile).
// Phase 2: Yout = bf16(ns * (h @ W)) via MFMA (A from LDS, B from L2-hot WT).

template<int NOUT>
__global__ __launch_bounds__(256)
void k_agg_gemm(const ushort* __restrict__ Yb, const int* __restrict__ rowptr,
                const int* __restrict__ csrc, const float* __restrict__ nd,
                const float* __restrict__ bias, const float* __restrict__ ns,
                const ushort* __restrict__ WT, float* __restrict__ hout,
                ushort* __restrict__ Yout) {
    constexpr int NT = NOUT / 64;
    __shared__ ushort sA[16][136];      // +8 bf16 pad breaks bank alignment
    int tid = threadIdx.x;
    int grp = tid >> 4;
    int lane = tid & 15;
    int node_base = blockIdx.x * 16;
    int node = node_base + grp;
    int beg = rowptr[node], end = rowptr[node + 1];
    float acc[8] = {0.f, 0.f, 0.f, 0.f, 0.f, 0.f, 0.f, 0.f};
    int e = beg;
    for (; e + 7 < end; e += 8) {              // 8 gathers in flight
        int s0 = csrc[e];     int s1 = csrc[e + 1];
        int s2 = csrc[e + 2]; int s3 = csrc[e + 3];
        int s4 = csrc[e + 4]; int s5 = csrc[e + 5];
        int s6 = csrc[e + 6]; int s7 = csrc[e + 7];
        uint4 q0 = *(const uint4*)(Yb + (size_t)s0 * 128 + lane * 8);
        uint4 q1 = *(const uint4*)(Yb + (size_t)s1 * 128 + lane * 8);
        uint4 q2 = *(const uint4*)(Yb + (size_t)s2 * 128 + lane * 8);
        uint4 q3 = *(const uint4*)(Yb + (size_t)s3 * 128 + lane * 8);
        uint4 q4 = *(const uint4*)(Yb + (size_t)s4 * 128 + lane * 8);
        uint4 q5 = *(const uint4*)(Yb + (size_t)s5 * 128 + lane * 8);
        uint4 q6 = *(const uint4*)(Yb + (size_t)s6 * 128 + lane * 8);
        uint4 q7 = *(const uint4*)(Yb + (size_t)s7 * 128 + lane * 8);
        bf8_add(q0, acc); bf8_add(q1, acc); bf8_add(q2, acc); bf8_add(q3, acc);
        bf8_add(q4, acc); bf8_add(q5, acc); bf8_add(q6, acc); bf8_add(q7, acc);
    }
    for (; e + 3 < end; e += 4) {
        int s0 = csrc[e];     int s1 = csrc[e + 1];
        int s2 = csrc[e + 2]; int s3 = csrc[e + 3];
        uint4 q0 = *(const uint4*)(Yb + (size_t)s0 * 128 + lane * 8);
        uint4 q1 = *(const uint4*)(Yb + (size_t)s1 * 128 + lane * 8);
        uint4 q2 = *(const uint4*)(Yb + (size_t)s2 * 128 + lane * 8);
        uint4 q3 = *(const uint4*)(Yb + (size_t)s3 * 128 + lane * 8);
        bf8_add(q0, acc); bf8_add(q1, acc); bf8_add(q2, acc); bf8_add(q3, acc);
    }
    for (; e < end; ++e) {
        uint4 q = *(const uint4*)(Yb + (size_t)csrc[e] * 128 + lane * 8);
        bf8_add(q, acc);
    }
    float ndv = nd[node];
    float4 b0 = *(const float4*)(bias + lane * 8);
    float4 b1 = *(const float4*)(bias + lane * 8 + 4);
    float o[8];
    o[0] = fmaxf(acc[0] * ndv + b0.x, 0.f); o[1] = fmaxf(acc[1] * ndv + b0.y, 0.f);
    o[2] = fmaxf(acc[2] * ndv + b0.z, 0.f); o[3] = fmaxf(acc[3] * ndv + b0.w, 0.f);
    o[4] = fmaxf(acc[4] * ndv + b1.x, 0.f); o[5] = fmaxf(acc[5] * ndv + b1.y, 0.f);
    o[6] = fmaxf(acc[6] * ndv + b1.z, 0.f); o[7] = fmaxf(acc[7] * ndv + b1.w, 0.f);
    *(float4*)(hout + (size_t)node * 128 + lane * 8)     = make_float4(o[0], o[1], o[2], o[3]);
    *(float4*)(hout + (size_t)node * 128 + lane * 8 + 4) = make_float4(o[4], o[5], o[6], o[7]);
    short8 ob;
    #pragma unroll
    for (int i = 0; i < 8; ++i) ob[i] = (short)f2bf(o[i]);
    *(short8*)&sA[grp][lane * 8] = ob;    // grp*272B + lane*16B: 16-B aligned
    __syncthreads();

    // phase 2: MFMA over the 16x128 LDS tile
    int w = tid >> 6;
    int l = tid & 63;
    int li = l & 15;
    int kg = l >> 4;
    short8 afrag[4];
    #pragma unroll
    for (int kt = 0; kt < 4; ++kt)
        afrag[kt] = *(const short8*)&sA[li][kt * 32 + kg * 8];
    float4 nsv = *(const float4*)(ns + node_base + kg * 4);
    float nsa[4] = {nsv.x, nsv.y, nsv.z, nsv.w};
    #pragma unroll
    for (int n = 0; n < NT; ++n) {
        int col = w * 16 * NT + n * 16 + li;
        short8 bfrag[4];
        #pragma unroll
        for (int kt = 0; kt < 4; ++kt)
            bfrag[kt] = *(const short8*)(WT + (size_t)col * 128 + kt * 32 + kg * 8);
        f32x4 acc2 = {0.f, 0.f, 0.f, 0.f};
        #pragma unroll
        for (int kt = 0; kt < 4; ++kt)
            acc2 = __builtin_amdgcn_mfma_f32_16x16x32_bf16(afrag[kt], bfrag[kt], acc2, 0, 0, 0);
        #pragma unroll
        for (int r = 0; r < 4; ++r)
            Yout[(size_t)(node_base + kg * 4 + r) * NOUT + col] = f2bf(acc2[r] * nsa[r]);
    }
}

// 256 thr = 32 groups x 8 lanes; one node per group; lane owns 8 of 64 feats.
__global__ __launch_bounds__(256)
void k_agg64(const ushort* __restrict__ Yb, const int* __restrict__ rowptr,
             const int* __restrict__ csrc, const float* __restrict__ nd,
             const float* __restrict__ bias, float* __restrict__ out) {
    int tid = threadIdx.x;
    int grp = tid >> 3;
    int lane = tid & 7;
    int node = blockIdx.x * 32 + grp;
    int beg = rowptr[node], end = rowptr[node + 1];
    float acc[8] = {0.f, 0.f, 0.f, 0.f, 0.f, 0.f, 0.f, 0.f};
    int e = beg;
    for (; e + 7 < end; e += 8) {
        int s0 = csrc[e];     int s1 = csrc[e + 1];
        int s2 = csrc[e + 2]; int s3 = csrc[e + 3];
        int s4 = csrc[e + 4]; int s5 = csrc[e + 5];
        int s6 = csrc[e + 6]; int s7 = csrc[e + 7];
        uint4 q0 = *(const uint4*)(Yb + (size_t)s0 * 64 + lane * 8);
        uint4 q1 = *(const uint4*)(Yb + (size_t)s1 * 64 + lane * 8);
        uint4 q2 = *(const uint4*)(Yb + (size_t)s2 * 64 + lane * 8);
        uint4 q3 = *(const uint4*)(Yb + (size_t)s3 * 64 + lane * 8);
        uint4 q4 = *(const uint4*)(Yb + (size_t)s4 * 64 + lane * 8);
        uint4 q5 = *(const uint4*)(Yb + (size_t)s5 * 64 + lane * 8);
        uint4 q6 = *(const uint4*)(Yb + (size_t)s6 * 64 + lane * 8);
        uint4 q7 = *(const uint4*)(Yb + (size_t)s7 * 64 + lane * 8);
        bf8_add(q0, acc); bf8_add(q1, acc); bf8_add(q2, acc); bf8_add(q3, acc);
        bf8_add(q4, acc); bf8_add(q5, acc); bf8_add(q6, acc); bf8_add(q7, acc);
    }
    for (; e + 3 < end; e += 4) {
        int s0 = csrc[e];     int s1 = csrc[e + 1];
        int s2 = csrc[e + 2]; int s3 = csrc[e + 3];
        uint4 q0 = *(const uint4*)(Yb + (size_t)s0 * 64 + lane * 8);
        uint4 q1 = *(const uint4*)(Yb + (size_t)s1 * 64 + lane * 8);
        uint4 q2 = *(const uint4*)(Yb + (size_t)s2 * 64 + lane * 8);
        uint4 q3 = *(const uint4*)(Yb + (size_t)s3 * 64 + lane * 8);
        bf8_add(q0, acc); bf8_add(q1, acc); bf8_add(q2, acc); bf8_add(q3, acc);
    }
    for (; e < end; ++e) {
        uint4 q = *(const uint4*)(Yb + (size_t)csrc[e] * 64 + lane * 8);
        bf8_add(q, acc);
    }
    float ndv = nd[node];
    float4 b0 = *(const float4*)(bias + lane * 8);
    float4 b1 = *(const float4*)(bias + lane * 8 + 4);
    float4 o0, o1;
    o0.x = acc[0] * ndv + b0.x; o0.y = acc[1] * ndv + b0.y;
    o0.z = acc[2] * ndv + b0.z; o0.w = acc[3] * ndv + b0.w;
    o1.x = acc[4] * ndv + b1.x; o1.y = acc[5] * ndv + b1.y;
    o1.z = acc[6] * ndv + b1.z; o1.w = acc[7] * ndv + b1.w;
    *(float4*)(out + (size_t)node * 64 + lane * 8)     = o0;
    *(float4*)(out + (size_t)node * 64 + lane * 8 + 4) = o1;
}

// ---------------- launch ----------------

extern "C" void kernel_launch(void* const* d_in, const int* in_sizes, int n_in,
                              void* d_out, int out_size, void* d_ws, size_t ws_size,
                              hipStream_t stream) {
    const float* x  = (const float*)d_in[0];
    const int* esrc = (const int*)d_in[1];
    const int* edst = (const int*)d_in[2];
    const float* W0 = (const float*)d_in[3];
    const float* b0 = (const float*)d_in[4];
    const float* W1 = (const float*)d_in[5];
    const float* b1 = (const float*)d_in[6];
    const float* W2 = (const float*)d_in[7];
    const float* b2 = (const float*)d_in[8];
    float* out = (float*)d_out;

    // workspace (~40 MB). No trailing backslashes in comments.
    float* ns      = (float*)d_ws;                // NN
    float* nd      = ns + NN;                     // NN
    int*   csum    = (int*)(nd + NN);             // NN
    int*   rowptr  = csum + NN;                   // NN+8
    int*   bsum    = rowptr + NN + 8;             // 512
    int*   bsumex  = bsum + 512;                  // 512
    int*   csrc    = bsumex + 512;                // NE
    uchar* pout    = (uchar*)(csrc + NE);         // KR*RSL*RS = 8 MB
    uchar* pin     = pout + (size_t)KR * RSL * RS;// 8 MB
    ushort* WT0    = (ushort*)(pin + (size_t)KR * RSL * RS);  // 128*128
    ushort* WT1    = WT0 + 128 * 128;             // 128*128
    ushort* WT2    = WT1 + 128 * 128;             // 64*128
    ushort* Y2b    = WT2 + 64 * 128;              // NN*64 bf16

    // output chunks
    float* h1 = out + (size_t)NN * 128;
    float* h2 = h1 + (size_t)NN * 128;
    float* h3 = h2 + (size_t)NN * 128;            // NN*64 floats

    // bf16 GEMM outputs parked in dead output slots:
    //  Y0b in h2 slot (last read: aggGemm layer1; h2 written layer2)
    //  Y1b in h3 slot (last read: aggGemm layer2; h3 written agg64)
    ushort* Y0b = (ushort*)h2;                    // NN*128 bf16
    ushort* Y1b = (ushort*)h3;                    // NN*128 bf16

    // 1. degree histograms (LDS-privatized, no global atomics)
    k_hist<<<KR * RSL, 256, 0, stream>>>(esrc, edst, pout, pin);

    // 2. reduce -> ns/nd/csum (+fused block sums); pin becomes r-prefix
    k_red<<<NB, 256, 0, stream>>>(pout, pin, ns, nd, csum, bsum);

    // 3. scan -> rowptr
    k_scanb<<<1, 512, 0, stream>>>(bsum, bsumex, rowptr);
    k_rowptr<<<NB, 256, 0, stream>>>(csum, bsumex, rowptr);

    // 4. fill CSR via LDS cursors (no global atomics)
    k_fill<<<KR * RSL, 256, 0, stream>>>(esrc, edst, pin, rowptr, csrc);

    // 5. weight transposes (one kernel)
    k_wtall<<<160, 256, 0, stream>>>(W0, W1, W2, WT0);

    // 6. layer-1 GEMM (reads fp32 x, fused out0 passthrough)
    k_gemm1<<<1024, 256, 0, stream>>>(x, WT0, ns, Y0b, out);

    // 7. fused agg(layer1)+GEMM(layer2): h1 + Y1b
    k_agg_gemm<128><<<NN / 16, 256, 0, stream>>>(Y0b, rowptr, csrc, nd, b0, ns,
                                                 WT1, h1, Y1b);

    // 8. fused agg(layer2)+GEMM(layer3): h2 + Y2b
    k_agg_gemm<64><<<NN / 16, 256, 0, stream>>>(Y1b, rowptr, csrc, nd, b1, ns,
                                                WT2, h2, Y2b);

    // 9. final aggregation -> h3
    k_agg64<<<NN / 32, 256, 0, stream>>>(Y2b, rowptr, csrc, nd, b2, h3);
}